// Round 4
// baseline (291.862 us; speedup 1.0000x reference)
//
#include <hip/hip_runtime.h>
#include <hip/hip_bf16.h>
#include <cstdint>
#include <cstddef>

typedef short short8 __attribute__((ext_vector_type(8)));
typedef short short4v __attribute__((ext_vector_type(4)));
typedef float floatx4 __attribute__((ext_vector_type(4)));
typedef unsigned short u16;
typedef unsigned int u32;

__device__ __forceinline__ u16 f2bf(float f) {
    __hip_bfloat16 h = __float2bfloat16(f);
    return __builtin_bit_cast(u16, h);
}

__device__ __forceinline__ floatx4 pv_mfma16(short4v a, short4v b, floatx4 c) {
#if __has_builtin(__builtin_amdgcn_mfma_f32_16x16x16bf16_1k)
    return __builtin_amdgcn_mfma_f32_16x16x16bf16_1k(a, b, c, 0, 0, 0);
#else
    floatx4 d = c;
    asm volatile("v_mfma_f32_16x16x16_bf16 %0, %1, %2, %0" : "+v"(d) : "v"(a), "v"(b));
    return d;
#endif
}

__device__ __forceinline__ void gload_lds16(const void* g, void* l) {
    __builtin_amdgcn_global_load_lds(
        (const __attribute__((address_space(1))) void*)g,
        (__attribute__((address_space(3))) void*)l, 16, 0, 0);
}

// ---------------- fp32 -> bf16 elementwise ----------------
__global__ __launch_bounds__(256) void cvt_x(const float* __restrict__ in, u16* __restrict__ out, int n4) {
    int stride = gridDim.x * blockDim.x;
    for (int i = blockIdx.x * blockDim.x + threadIdx.x; i < n4; i += stride) {
        float4 v = ((const float4*)in)[i];
        ushort4 o;
        o.x = f2bf(v.x); o.y = f2bf(v.y); o.z = f2bf(v.z); o.w = f2bf(v.w);
        ((ushort4*)out)[i] = o;
    }
}

// ---------------- W[K][N] f32 -> Wt[N][K] bf16 ----------------
__global__ __launch_bounds__(256) void transpose_cvt(const float* __restrict__ W, u16* __restrict__ Wt,
                                                     int K, int N) {
    __shared__ float tile[32][33];
    int n0 = blockIdx.x * 32, k0 = blockIdx.y * 32;
    int tx = threadIdx.x & 31, ty = threadIdx.x >> 5;  // ty 0..7
    #pragma unroll
    for (int i = 0; i < 32; i += 8)
        tile[ty + i][tx] = W[(size_t)(k0 + ty + i) * N + n0 + tx];
    __syncthreads();
    #pragma unroll
    for (int i = 0; i < 32; i += 8)
        Wt[(size_t)(n0 + ty + i) * K + k0 + tx] = f2bf(tile[tx][ty + i]);
}

// ---------------- bf16 GEMM: C[M][N] = A[M][K] * Bt[N][K]^T ----------------
// MODE: 0 = f32 [M][N], 1 = bf16 [M][N], 2 = bf16 per-head packed [b][h][t][64],
//       3 = kv split: col<1024 -> K per-head packed; col>=1024 -> V transposed [b][h][d][t]
//       4 = q+latent fused: col<1024 -> per-head packed q; col>=1024 -> latent [M][128] appended after q
template <int MODE>
__global__ __launch_bounds__(256) void gemm_bt(const u16* __restrict__ A, const u16* __restrict__ Bt,
                                               void* __restrict__ C, int M, int N, int K) {
    __shared__ u16 As[128 * 32];
    __shared__ u16 Bs[128 * 32];
    const int tid = threadIdx.x;
    const int lane = tid & 63, wid = tid >> 6;
    const int m0 = blockIdx.x * 128, n0 = blockIdx.y * 128;
    const int wr = wid >> 1, wc = wid & 1;

    floatx4 acc[4][4] = {};

    const int c0 = tid, c1 = tid + 256;
    const u16* Ab = A + (size_t)m0 * K;
    const u16* Bb = Bt + (size_t)n0 * K;
    const size_t off0 = (size_t)(c0 >> 2) * K + (size_t)(c0 & 3) * 8;
    const size_t off1 = (size_t)(c1 >> 2) * K + (size_t)(c1 & 3) * 8;
    u16* As0 = &As[(wid * 64) * 8];
    u16* As1 = &As[(wid * 64 + 256) * 8];
    u16* Bs0 = &Bs[(wid * 64) * 8];
    u16* Bs1 = &Bs[(wid * 64 + 256) * 8];

    for (int k0 = 0; k0 < K; k0 += 32) {
        gload_lds16(Ab + off0 + k0, As0);
        gload_lds16(Ab + off1 + k0, As1);
        gload_lds16(Bb + off0 + k0, Bs0);
        gload_lds16(Bb + off1 + k0, Bs1);
        __syncthreads();
        short8 af[4], bfr[4];
        const u16* AsW = &As[(wr * 64) * 32];
        const u16* BsW = &Bs[(wc * 64) * 32];
        #pragma unroll
        for (int i = 0; i < 4; i++)
            af[i] = *(const short8*)&AsW[(i * 16 + (lane & 15)) * 32 + (lane >> 4) * 8];
        #pragma unroll
        for (int j = 0; j < 4; j++)
            bfr[j] = *(const short8*)&BsW[(j * 16 + (lane & 15)) * 32 + (lane >> 4) * 8];
        #pragma unroll
        for (int i = 0; i < 4; i++) {
            #pragma unroll
            for (int j = 0; j < 4; j++)
                acc[i][j] = __builtin_amdgcn_mfma_f32_16x16x32_bf16(af[i], bfr[j], acc[i][j], 0, 0, 0);
        }
        __syncthreads();
    }

    const int cr = (lane >> 4) * 4, cc = lane & 15;
    #pragma unroll
    for (int i = 0; i < 4; i++) {
        #pragma unroll
        for (int j = 0; j < 4; j++) {
            int row = m0 + wr * 64 + i * 16 + cr;
            int col = n0 + wc * 64 + j * 16 + cc;
            #pragma unroll
            for (int r = 0; r < 4; r++) {
                float v = acc[i][j][r];
                int rr = row + r;
                if (MODE == 0) {
                    ((float*)C)[(size_t)rr * N + col] = v;
                } else if (MODE == 1) {
                    ((u16*)C)[(size_t)rr * N + col] = f2bf(v);
                } else if (MODE == 2) {
                    int h = col >> 6, dd = col & 63;
                    ((u16*)C)[(((size_t)(rr >> 8) * 16 + h) * 256 + (rr & 255)) * 64 + dd] = f2bf(v);
                } else if (MODE == 3) {
                    if (col < 1024) {
                        int h = col >> 6, dd = col & 63;
                        ((u16*)C)[(((size_t)(rr >> 8) * 16 + h) * 256 + (rr & 255)) * 64 + dd] = f2bf(v);
                    } else {
                        int d = col - 1024;
                        int h = d >> 6, dd = d & 63;
                        u16* vt = (u16*)C + (size_t)16384 * 1024;
                        vt[(((size_t)(rr >> 8) * 16 + h) * 64 + dd) * 256 + (rr & 255)] = f2bf(v);
                    }
                } else {  // MODE 4
                    if (col < 1024) {
                        int h = col >> 6, dd = col & 63;
                        ((u16*)C)[(((size_t)(rr >> 8) * 16 + h) * 256 + (rr & 255)) * 64 + dd] = f2bf(v);
                    } else {
                        u16* lat = (u16*)C + (size_t)16384 * 1024;
                        lat[(size_t)rr * 128 + (col - 1024)] = f2bf(v);
                    }
                }
            }
        }
    }
}

// ---------------- causal attention ----------------
// One block per (b,h). 256 threads = 4 waves. Qh/Kh packed [b][h][t][64], Vtg packed [b][h][d][t].
// Swapped QK^T: s-tile = mfma(K_frag, Q_frag) -> lane owns q = lane&15, k = 16kt+4hi+r.
// P stays in registers (exact A-frag layout of 16x16x16 MFMA); PV reads V as ds_read_b64 from Vt.
// LDS = Vt only (33.8 KB) -> 4 blocks/CU.
__global__ __launch_bounds__(256) void attn_kernel(const u16* __restrict__ Qh, const u16* __restrict__ Kh,
                                                   const u16* __restrict__ Vtg, u16* __restrict__ Y) {
    constexpr int T = 256, HD = 1024;
    constexpr int VS = 264;  // Vt row stride (16B-aligned rows, odd 16B count -> spreads banks)
    __shared__ __align__(16) u16 Vt[64 * VS];

    const int tid = threadIdx.x, lane = tid & 63, wid = tid >> 6;
    const int bh = blockIdx.x;
    const size_t base = (size_t)bh * (T * 64);  // 16384 elements per (b,h)
    const size_t baseY = (size_t)(bh >> 4) * T * HD + (size_t)(bh & 15) * 64;

    // stage Vt[d][t] from pre-transposed global (coalesced 16B chunks)
    {
        const u16* vsrc = Vtg + base;
        #pragma unroll
        for (int it = 0; it < 8; it++) {
            int idx = tid + it * 256;       // 0..2047
            int d = idx >> 5, t0 = (idx & 31) * 8;
            *(short8*)&Vt[d * VS + t0] = *(const short8*)&vsrc[d * 256 + t0];
        }
    }
    __syncthreads();

    const float c_exp = 0.125f * 1.44269504088896f;  // scale * log2(e)
    const int kc = lane & 15;           // q-local for scores; col index elsewhere
    const int hi = lane >> 4, qq = hi * 4, hi8 = hi * 8;
    const u16* kbase = Kh + base;
    const u16* qbase = Qh + base;

    #pragma unroll 1
    for (int ii = 0; ii < 4; ii++) {
        const int st = wid + ii * 4;   // q subtile index 0..15 (wave-uniform)
        const int q0 = st * 16;

        short8 qf0, qf1;
        {
            const u16* qp = &qbase[(size_t)(q0 + kc) * 64 + hi8];
            qf0 = *(const short8*)qp;
            qf1 = *(const short8*)(qp + 32);
        }

        // ---- swapped QK^T: lane holds S[k=16kt+qq+r][q=q0+kc] ----
        floatx4 s[16];
        #pragma unroll
        for (int kt = 0; kt < 16; kt++) {
            if (kt > st) continue;
            const u16* kp = &kbase[(size_t)(kt * 16 + kc) * 64 + hi8];
            short8 kf0 = *(const short8*)kp;
            short8 kf1 = *(const short8*)(kp + 32);
            floatx4 z = {0.f, 0.f, 0.f, 0.f};
            z = __builtin_amdgcn_mfma_f32_16x16x32_bf16(kf0, qf0, z, 0, 0, 0);
            s[kt] = __builtin_amdgcn_mfma_f32_16x16x32_bf16(kf1, qf1, z, 0, 0, 0);
            if (kt == st) {
                #pragma unroll
                for (int r = 0; r < 4; r++)
                    if (qq + r > kc) s[kt][r] = -INFINITY;  // k > q -> mask
            }
        }

        // ---- row max (per-lane scalar; reduce over the 4 hi-groups) ----
        float mx = -1e30f;
        #pragma unroll
        for (int kt = 0; kt < 16; kt++) {
            if (kt > st) continue;
            #pragma unroll
            for (int r = 0; r < 4; r++) mx = fmaxf(mx, s[kt][r]);
        }
        mx = fmaxf(mx, __shfl_xor(mx, 16));
        mx = fmaxf(mx, __shfl_xor(mx, 32));

        // ---- exp, sum, pack P to bf16 pairs (A-frag layout of 16x16x16) ----
        float psum = 0.f;
        u32 pp0[16], pp1[16];
        #pragma unroll
        for (int kt = 0; kt < 16; kt++) {
            if (kt > st) continue;
            float p0 = exp2f((s[kt][0] - mx) * c_exp);
            float p1 = exp2f((s[kt][1] - mx) * c_exp);
            float p2 = exp2f((s[kt][2] - mx) * c_exp);
            float p3 = exp2f((s[kt][3] - mx) * c_exp);
            psum += (p0 + p1) + (p2 + p3);
            pp0[kt] = (u32)f2bf(p0) | ((u32)f2bf(p1) << 16);
            pp1[kt] = (u32)f2bf(p2) | ((u32)f2bf(p3) << 16);
        }
        psum += __shfl_xor(psum, 16);
        psum += __shfl_xor(psum, 32);

        // ---- PV: y[q][d] += P[q][k] * V[k][d], 16x16x16 MFMA per (kt,dt) ----
        floatx4 y[4] = {};
        #pragma unroll
        for (int kt = 0; kt < 16; kt++) {
            if (kt > st) continue;
            int2 ppk; ppk.x = (int)pp0[kt]; ppk.y = (int)pp1[kt];
            short4v pa = __builtin_bit_cast(short4v, ppk);
            const u16* vrow = &Vt[kt * 16 + qq];
            #pragma unroll
            for (int dt = 0; dt < 4; dt++) {
                short4v vf = *(const short4v*)&vrow[(dt * 16 + kc) * VS];
                y[dt] = pv_mfma16(pa, vf, y[dt]);
            }
        }

        // ---- normalize: lane needs row-sums for q = q0+qq+r ----
        float rinv[4];
        #pragma unroll
        for (int r = 0; r < 4; r++) rinv[r] = 1.0f / __shfl(psum, qq + r, 64);
        #pragma unroll
        for (int dt = 0; dt < 4; dt++) {
            #pragma unroll
            for (int r = 0; r < 4; r++)
                Y[baseY + (size_t)(q0 + qq + r) * HD + dt * 16 + kc] = f2bf(y[dt][r] * rinv[r]);
        }
    }
}

extern "C" void kernel_launch(void* const* d_in, const int* in_sizes, int n_in,
                              void* d_out, int out_size, void* d_ws, size_t ws_size,
                              hipStream_t stream) {
    const float* x         = (const float*)d_in[0];
    const float* w_kv_down = (const float*)d_in[1];
    const float* w_kv_up   = (const float*)d_in[2];
    const float* w_q       = (const float*)d_in[3];
    const float* w_out     = (const float*)d_in[4];
    float* out = (float*)d_out;

    constexpr int Bb = 64, Tt = 256, Cc = 1024, HD = 1024, R = 128;
    constexpr int M = Bb * Tt;  // 16384

    char* ws = (char*)d_ws;
    auto alloc = [&](size_t bytes) {
        void* p = (void*)ws;
        ws += (bytes + 255) & ~(size_t)255;
        return p;
    };
    u16* xb      = (u16*)alloc((size_t)M * Cc * 2);
    u16* wql_t   = (u16*)alloc((size_t)(HD + R) * Cc * 2);  // rows 0..1023 = Wq^T, 1024..1151 = Wkv_down^T
    u16* wkvu_t  = (u16*)alloc((size_t)2 * HD * R * 2);
    u16* wo_t    = (u16*)alloc((size_t)Cc * HD * 2);
    u16* qh      = (u16*)alloc((size_t)M * HD * 2);      // per-head packed q  [b][h][t][64]
    u16* latentb = (u16*)alloc((size_t)M * R * 2);       // MUST stay contiguous after qh (MODE 4)
    u16* kvb     = (u16*)alloc((size_t)M * 2 * HD * 2);  // kh [b][h][t][64] then vt [b][h][d][t]
    u16* yb      = (u16*)alloc((size_t)M * HD * 2);

    u16* kh  = kvb;
    u16* vtg = kvb + (size_t)M * HD;

    cvt_x<<<2048, 256, 0, stream>>>(x, xb, M * Cc / 4);
    transpose_cvt<<<dim3(HD / 32, Cc / 32), 256, 0, stream>>>(w_q, wql_t, Cc, HD);
    transpose_cvt<<<dim3(R / 32, Cc / 32), 256, 0, stream>>>(w_kv_down, wql_t + (size_t)HD * Cc, Cc, R);
    transpose_cvt<<<dim3(2 * HD / 32, R / 32), 256, 0, stream>>>(w_kv_up, wkvu_t, R, 2 * HD);
    transpose_cvt<<<dim3(Cc / 32, HD / 32), 256, 0, stream>>>(w_out, wo_t, HD, Cc);

    // q + latent fused: (M x 1152 x 1024); cols 0..1023 -> qh (packed), 1024..1151 -> latentb
    gemm_bt<4><<<dim3(M / 128, (HD + R) / 128), 256, 0, stream>>>(xb, wql_t, qh, M, HD + R, Cc);
    // kv = latent @ Wkv_up    (M x 2048 x 128) -> K per-head packed + V transposed
    gemm_bt<3><<<dim3(M / 128, 2 * HD / 128), 256, 0, stream>>>(latentb, wkvu_t, kvb, M, 2 * HD, R);
    // attention
    attn_kernel<<<Bb * 16, 256, 0, stream>>>(qh, kh, vtg, yb);
    // out = y @ Wout          (M x 1024 x 1024), fp32 [M][1024]
    gemm_bt<0><<<dim3(M / 128, Cc / 128), 256, 0, stream>>>(yb, wo_t, out, M, Cc, HD);
}

// Round 5
// 282.895 us; speedup vs baseline: 1.0317x; 1.0317x over previous
//
#include <hip/hip_runtime.h>
#include <hip/hip_bf16.h>
#include <cstdint>
#include <cstddef>

typedef short short8 __attribute__((ext_vector_type(8)));
typedef float floatx4 __attribute__((ext_vector_type(4)));
typedef float floatx16 __attribute__((ext_vector_type(16)));
typedef int intx4 __attribute__((ext_vector_type(4)));
typedef unsigned short u16;
typedef unsigned int u32;

__device__ __forceinline__ u16 f2bf(float f) {
    __hip_bfloat16 h = __float2bfloat16(f);
    return __builtin_bit_cast(u16, h);
}

__device__ __forceinline__ void gload_lds16(const void* g, void* l) {
    __builtin_amdgcn_global_load_lds(
        (const __attribute__((address_space(1))) void*)g,
        (__attribute__((address_space(3))) void*)l, 16, 0, 0);
}

// ---------------- fp32 -> bf16 elementwise ----------------
__global__ __launch_bounds__(256) void cvt_x(const float* __restrict__ in, u16* __restrict__ out, int n4) {
    int stride = gridDim.x * blockDim.x;
    for (int i = blockIdx.x * blockDim.x + threadIdx.x; i < n4; i += stride) {
        float4 v = ((const float4*)in)[i];
        ushort4 o;
        o.x = f2bf(v.x); o.y = f2bf(v.y); o.z = f2bf(v.z); o.w = f2bf(v.w);
        ((ushort4*)out)[i] = o;
    }
}

// ---------------- W[K][N] f32 -> Wt[N][K] bf16 ----------------
__global__ __launch_bounds__(256) void transpose_cvt(const float* __restrict__ W, u16* __restrict__ Wt,
                                                     int K, int N) {
    __shared__ float tile[32][33];
    int n0 = blockIdx.x * 32, k0 = blockIdx.y * 32;
    int tx = threadIdx.x & 31, ty = threadIdx.x >> 5;  // ty 0..7
    #pragma unroll
    for (int i = 0; i < 32; i += 8)
        tile[ty + i][tx] = W[(size_t)(k0 + ty + i) * N + n0 + tx];
    __syncthreads();
    #pragma unroll
    for (int i = 0; i < 32; i += 8)
        Wt[(size_t)(n0 + ty + i) * K + k0 + tx] = f2bf(tile[tx][ty + i]);
}

// ---------------- bf16 GEMM: C[M][N] = A[M][K] * Bt[N][K]^T ----------------
// LDS layout: fragment-ordered [i-block][lane][8] so each wave fragment read is
// base + lane*16B (conflict-free). Staging keeps LDS dest linear (global_load_lds
// rule) and permutes the GLOBAL source offset instead.
// MODE: 0 = f32 [M][N], 1 = bf16 [M][N], 2 = bf16 per-head packed [b][h][t][64],
//       3 = kv split: col<1024 -> K per-head packed; col>=1024 -> V transposed [b][h][d][t]
//       4 = q+latent fused: col<1024 -> per-head packed q; col>=1024 -> latent [M][128]
template <int MODE>
__global__ __launch_bounds__(256) void gemm_bt(const u16* __restrict__ A, const u16* __restrict__ Bt,
                                               void* __restrict__ C, int M, int N, int K) {
    __shared__ u16 As[128 * 32];
    __shared__ u16 Bs[128 * 32];
    const int tid = threadIdx.x;
    const int lane = tid & 63, wid = tid >> 6;
    const int m0 = blockIdx.x * 128, n0 = blockIdx.y * 128;
    const int wr = wid >> 1, wc = wid & 1;

    floatx4 acc[4][4] = {};

    const int c0 = tid, c1 = tid + 256;
    const u16* Ab = A + (size_t)m0 * K;
    const u16* Bb = Bt + (size_t)n0 * K;
    // chunk c -> (i = c>>6, hi = (c>>4)&3, kc = c&15); global row = i*16+kc, col = hi*8
    const size_t off0 = (size_t)(((c0 >> 6) << 4) + (c0 & 15)) * K + (size_t)((c0 >> 4) & 3) * 8;
    const size_t off1 = (size_t)(((c1 >> 6) << 4) + (c1 & 15)) * K + (size_t)((c1 >> 4) & 3) * 8;
    u16* As0 = &As[(wid * 64) * 8];
    u16* As1 = &As[(wid * 64 + 256) * 8];
    u16* Bs0 = &Bs[(wid * 64) * 8];
    u16* Bs1 = &Bs[(wid * 64 + 256) * 8];

    for (int k0 = 0; k0 < K; k0 += 32) {
        gload_lds16(Ab + off0 + k0, As0);
        gload_lds16(Ab + off1 + k0, As1);
        gload_lds16(Bb + off0 + k0, Bs0);
        gload_lds16(Bb + off1 + k0, Bs1);
        __syncthreads();
        short8 af[4], bfr[4];
        #pragma unroll
        for (int i = 0; i < 4; i++)
            af[i] = *(const short8*)&As[((wr * 4 + i) * 64 + lane) * 8];
        #pragma unroll
        for (int j = 0; j < 4; j++)
            bfr[j] = *(const short8*)&Bs[((wc * 4 + j) * 64 + lane) * 8];
        #pragma unroll
        for (int i = 0; i < 4; i++) {
            #pragma unroll
            for (int j = 0; j < 4; j++)
                acc[i][j] = __builtin_amdgcn_mfma_f32_16x16x32_bf16(af[i], bfr[j], acc[i][j], 0, 0, 0);
        }
        __syncthreads();
    }

    const int cr = (lane >> 4) * 4, cc = lane & 15;
    #pragma unroll
    for (int i = 0; i < 4; i++) {
        #pragma unroll
        for (int j = 0; j < 4; j++) {
            int row = m0 + wr * 64 + i * 16 + cr;
            int col = n0 + wc * 64 + j * 16 + cc;
            #pragma unroll
            for (int r = 0; r < 4; r++) {
                float v = acc[i][j][r];
                int rr = row + r;
                if (MODE == 0) {
                    ((float*)C)[(size_t)rr * N + col] = v;
                } else if (MODE == 1) {
                    ((u16*)C)[(size_t)rr * N + col] = f2bf(v);
                } else if (MODE == 2) {
                    int h = col >> 6, dd = col & 63;
                    ((u16*)C)[(((size_t)(rr >> 8) * 16 + h) * 256 + (rr & 255)) * 64 + dd] = f2bf(v);
                } else if (MODE == 3) {
                    if (col < 1024) {
                        int h = col >> 6, dd = col & 63;
                        ((u16*)C)[(((size_t)(rr >> 8) * 16 + h) * 256 + (rr & 255)) * 64 + dd] = f2bf(v);
                    } else {
                        int d = col - 1024;
                        int h = d >> 6, dd = d & 63;
                        u16* vt = (u16*)C + (size_t)16384 * 1024;
                        vt[(((size_t)(rr >> 8) * 16 + h) * 64 + dd) * 256 + (rr & 255)] = f2bf(v);
                    }
                } else {  // MODE 4
                    if (col < 1024) {
                        int h = col >> 6, dd = col & 63;
                        ((u16*)C)[(((size_t)(rr >> 8) * 16 + h) * 256 + (rr & 255)) * 64 + dd] = f2bf(v);
                    } else {
                        u16* lat = (u16*)C + (size_t)16384 * 1024;
                        lat[(size_t)rr * 128 + (col - 1024)] = f2bf(v);
                    }
                }
            }
        }
    }
}

// ---------------- causal attention (32x32x16 structure) ----------------
// One block per (b,h), 4 waves. Wave w handles q-blocks {w, 7-w} (balanced: 9 k-tiles).
// Swapped QK^T: s = mfma(K,Q) -> lane owns col q=lane&31, rows k=(r&3)+8(r>>2)+4*hi2.
// P packed to bf16 pairs; permlane32_swap builds the PV A-fragment in-register.
// No max-subtraction (scores bounded ~|9| by construction); single end-of-row sum reduce.
// LDS = Vt only (33.8 KB).
__global__ __launch_bounds__(256, 3) void attn_kernel(const u16* __restrict__ Qh, const u16* __restrict__ Kh,
                                                      const u16* __restrict__ Vtg, u16* __restrict__ Y) {
    constexpr int T = 256, HD = 1024;
    constexpr int VS = 264;  // Vt row stride (16B-aligned rows)
    __shared__ __align__(16) u16 Vt[64 * VS];

    const int tid = threadIdx.x, lane = tid & 63, wid = tid >> 6;
    const int bh = blockIdx.x;
    const size_t base = (size_t)bh * (T * 64);
    const size_t baseY = (size_t)(bh >> 4) * T * HD + (size_t)(bh & 15) * 64;

    // stage Vt[d][t] from pre-transposed global (coalesced 16B chunks)
    {
        const u16* vsrc = Vtg + base;
        #pragma unroll
        for (int it = 0; it < 8; it++) {
            int idx = tid + it * 256;       // 0..2047
            int d = idx >> 5, t0 = (idx & 31) * 8;
            *(short8*)&Vt[d * VS + t0] = *(const short8*)&vsrc[d * 256 + t0];
        }
    }
    __syncthreads();

    const float c_exp = 0.125f * 1.44269504088896f;  // scale * log2(e)
    const int qcol = lane & 31, hi2 = lane >> 5;
    const u16* kbase = Kh + base;
    const u16* qbase = Qh + base;
    const u16* vrow0 = &Vt[qcol * VS];
    const u16* vrow1 = &Vt[(qcol + 32) * VS];

    #pragma unroll 1
    for (int half = 0; half < 2; half++) {
        const int qb = half ? (7 - wid) : wid;   // wave-uniform q-block 0..7

        short8 qf[4];
        {
            const u16* qp = &qbase[(size_t)(qb * 32 + qcol) * 64 + hi2 * 8];
            #pragma unroll
            for (int i = 0; i < 4; i++) qf[i] = *(const short8*)&qp[i * 16];
        }

        floatx16 y0 = {0}, y1 = {0};
        float lsum = 0.f;

        for (int kt = 0; kt <= qb; kt++) {
            // ---- QK^T (swapped): S[k][q], contraction over d=64 in 4 chunks ----
            const u16* kp = &kbase[(size_t)(kt * 32 + qcol) * 64 + hi2 * 8];
            floatx16 s = {0};
            #pragma unroll
            for (int i = 0; i < 4; i++) {
                short8 kf = *(const short8*)&kp[i * 16];
                s = __builtin_amdgcn_mfma_f32_32x32x16_bf16(kf, qf[i], s, 0, 0, 0);
            }

            // ---- exp (no max-sub), causal mask on diagonal tile, pack bf16 pairs ----
            const bool diag = (kt == qb);
            u32 pk[8];
            #pragma unroll
            for (int r2 = 0; r2 < 8; r2++) {
                const int r0 = 2 * r2;
                const int kr0 = (r0 & 3) + 8 * (r0 >> 2) + 4 * hi2;  // k-row of reg r0
                float p0 = exp2f(s[r0] * c_exp);
                float p1 = exp2f(s[r0 + 1] * c_exp);
                if (diag) {
                    if (kr0 > qcol) p0 = 0.f;
                    if (kr0 + 1 > qcol) p1 = 0.f;
                }
                lsum += p0 + p1;
                pk[r2] = (u32)f2bf(p0) | ((u32)f2bf(p1) << 16);
            }

            // ---- PV: build A-frag via permlane32_swap, 2 k-halves x 2 d-tiles ----
            #pragma unroll
            for (int kh2 = 0; kh2 < 2; kh2++) {
                u32 a0 = pk[kh2 * 4 + 0], a1 = pk[kh2 * 4 + 1];
                u32 b0 = pk[kh2 * 4 + 2], b1 = pk[kh2 * 4 + 3];
                asm volatile("v_permlane32_swap_b32 %0, %1" : "+v"(a0), "+v"(b0));
                asm volatile("v_permlane32_swap_b32 %0, %1" : "+v"(a1), "+v"(b1));
                intx4 w;
                w[0] = (int)a0; w[1] = (int)a1; w[2] = (int)b0; w[3] = (int)b1;
                short8 pa = __builtin_bit_cast(short8, w);
                const int tofs = kt * 32 + kh2 * 16 + hi2 * 8;
                short8 vf0 = *(const short8*)&vrow0[tofs];
                short8 vf1 = *(const short8*)&vrow1[tofs];
                y0 = __builtin_amdgcn_mfma_f32_32x32x16_bf16(pa, vf0, y0, 0, 0, 0);
                y1 = __builtin_amdgcn_mfma_f32_32x32x16_bf16(pa, vf1, y1, 0, 0, 0);
            }
        }

        // ---- row sums (lane q and q+32 hold partials for column q) ----
        lsum += __shfl_xor(lsum, 32);
        const float linv = 1.0f / lsum;

        float sc[16];
        #pragma unroll
        for (int r = 0; r < 16; r++)
            sc[r] = __shfl(linv, (r & 3) + 8 * (r >> 2) + 4 * hi2, 64);

        #pragma unroll
        for (int r = 0; r < 16; r++) {
            const int qloc = (r & 3) + 8 * (r >> 2) + 4 * hi2;
            const size_t rowoff = baseY + (size_t)(qb * 32 + qloc) * HD;
            Y[rowoff + qcol]      = f2bf(y0[r] * sc[r]);
            Y[rowoff + 32 + qcol] = f2bf(y1[r] * sc[r]);
        }
    }
}

extern "C" void kernel_launch(void* const* d_in, const int* in_sizes, int n_in,
                              void* d_out, int out_size, void* d_ws, size_t ws_size,
                              hipStream_t stream) {
    const float* x         = (const float*)d_in[0];
    const float* w_kv_down = (const float*)d_in[1];
    const float* w_kv_up   = (const float*)d_in[2];
    const float* w_q       = (const float*)d_in[3];
    const float* w_out     = (const float*)d_in[4];
    float* out = (float*)d_out;

    constexpr int Bb = 64, Tt = 256, Cc = 1024, HD = 1024, R = 128;
    constexpr int M = Bb * Tt;  // 16384

    char* ws = (char*)d_ws;
    auto alloc = [&](size_t bytes) {
        void* p = (void*)ws;
        ws += (bytes + 255) & ~(size_t)255;
        return p;
    };
    u16* xb      = (u16*)alloc((size_t)M * Cc * 2);
    u16* wql_t   = (u16*)alloc((size_t)(HD + R) * Cc * 2);  // rows 0..1023 = Wq^T, 1024..1151 = Wkv_down^T
    u16* wkvu_t  = (u16*)alloc((size_t)2 * HD * R * 2);
    u16* wo_t    = (u16*)alloc((size_t)Cc * HD * 2);
    u16* qh      = (u16*)alloc((size_t)M * HD * 2);      // per-head packed q  [b][h][t][64]
    u16* latentb = (u16*)alloc((size_t)M * R * 2);       // MUST stay contiguous after qh (MODE 4)
    u16* kvb     = (u16*)alloc((size_t)M * 2 * HD * 2);  // kh [b][h][t][64] then vt [b][h][d][t]
    u16* yb      = (u16*)alloc((size_t)M * HD * 2);

    u16* kh  = kvb;
    u16* vtg = kvb + (size_t)M * HD;

    cvt_x<<<2048, 256, 0, stream>>>(x, xb, M * Cc / 4);
    transpose_cvt<<<dim3(HD / 32, Cc / 32), 256, 0, stream>>>(w_q, wql_t, Cc, HD);
    transpose_cvt<<<dim3(R / 32, Cc / 32), 256, 0, stream>>>(w_kv_down, wql_t + (size_t)HD * Cc, Cc, R);
    transpose_cvt<<<dim3(2 * HD / 32, R / 32), 256, 0, stream>>>(w_kv_up, wkvu_t, R, 2 * HD);
    transpose_cvt<<<dim3(Cc / 32, HD / 32), 256, 0, stream>>>(w_out, wo_t, HD, Cc);

    // q + latent fused: (M x 1152 x 1024); cols 0..1023 -> qh (packed), 1024..1151 -> latentb
    gemm_bt<4><<<dim3(M / 128, (HD + R) / 128), 256, 0, stream>>>(xb, wql_t, qh, M, HD + R, Cc);
    // kv = latent @ Wkv_up    (M x 2048 x 128) -> K per-head packed + V transposed
    gemm_bt<3><<<dim3(M / 128, 2 * HD / 128), 256, 0, stream>>>(latentb, wkvu_t, kvb, M, 2 * HD, R);
    // attention
    attn_kernel<<<Bb * 16, 256, 0, stream>>>(qh, kh, vtg, yb);
    // out = y @ Wout          (M x 1024 x 1024), fp32 [M][1024]
    gemm_bt<0><<<dim3(M / 128, Cc / 128), 256, 0, stream>>>(yb, wo_t, out, M, Cc, HD);
}

// Round 6
// 227.289 us; speedup vs baseline: 1.2841x; 1.2446x over previous
//
#include <hip/hip_runtime.h>
#include <hip/hip_bf16.h>
#include <cstdint>
#include <cstddef>

typedef short short8 __attribute__((ext_vector_type(8)));
typedef float floatx4 __attribute__((ext_vector_type(4)));
typedef float floatx16 __attribute__((ext_vector_type(16)));
typedef int intx4 __attribute__((ext_vector_type(4)));
typedef unsigned short u16;
typedef unsigned int u32;

__device__ __forceinline__ u16 f2bf(float f) {
    __hip_bfloat16 h = __float2bfloat16(f);
    return __builtin_bit_cast(u16, h);
}

__device__ __forceinline__ void gload_lds16(const void* g, void* l) {
    __builtin_amdgcn_global_load_lds(
        (const __attribute__((address_space(1))) void*)g,
        (__attribute__((address_space(3))) void*)l, 16, 0, 0);
}

// ---------------- fp32 -> bf16 elementwise ----------------
__global__ __launch_bounds__(256) void cvt_x(const float* __restrict__ in, u16* __restrict__ out, int n4) {
    int stride = gridDim.x * blockDim.x;
    for (int i = blockIdx.x * blockDim.x + threadIdx.x; i < n4; i += stride) {
        float4 v = ((const float4*)in)[i];
        ushort4 o;
        o.x = f2bf(v.x); o.y = f2bf(v.y); o.z = f2bf(v.z); o.w = f2bf(v.w);
        ((ushort4*)out)[i] = o;
    }
}

// ---------------- W[K][N] f32 -> Wt[N][K] bf16 ----------------
__global__ __launch_bounds__(256) void transpose_cvt(const float* __restrict__ W, u16* __restrict__ Wt,
                                                     int K, int N) {
    __shared__ float tile[32][33];
    int n0 = blockIdx.x * 32, k0 = blockIdx.y * 32;
    int tx = threadIdx.x & 31, ty = threadIdx.x >> 5;  // ty 0..7
    #pragma unroll
    for (int i = 0; i < 32; i += 8)
        tile[ty + i][tx] = W[(size_t)(k0 + ty + i) * N + n0 + tx];
    __syncthreads();
    #pragma unroll
    for (int i = 0; i < 32; i += 8)
        Wt[(size_t)(n0 + ty + i) * K + k0 + tx] = f2bf(tile[tx][ty + i]);
}

// ---------------- bf16 GEMM: C[M][N] = A[M][K] * Bt[N][K]^T ----------------
// LDS chunk mapping: pos p holds row-major chunk c = p ^ ((p>>3)&3)  (involution;
// XOR flips bits 0-1 using untouched bits 3-4). Write side: within each lane quad
// p>>3 is constant, so global reads stay 64B-contiguous per row (coalesced).
// Read side: fragment chunk c -> pos p = c ^ ((c>>3)&3) spreads the 16-lane phase
// over all 8 bank-quads (2-way max = free).
// MODE: 0 = f32 [M][N], 1 = bf16 [M][N], 2 = bf16 per-head packed [b][h][t][64],
//       3 = kv split: col<1024 -> K per-head packed; col>=1024 -> V transposed [b][h][d][t]
//       4 = q+latent fused: col<1024 -> per-head packed q; col>=1024 -> latent [M][128]
template <int MODE>
__global__ __launch_bounds__(256) void gemm_bt(const u16* __restrict__ A, const u16* __restrict__ Bt,
                                               void* __restrict__ C, int M, int N, int K) {
    __shared__ u16 As[128 * 32];
    __shared__ u16 Bs[128 * 32];
    const int tid = threadIdx.x;
    const int lane = tid & 63, wid = tid >> 6;
    const int m0 = blockIdx.x * 128, n0 = blockIdx.y * 128;
    const int wr = wid >> 1, wc = wid & 1;

    floatx4 acc[4][4] = {};

    const u16* Ab = A + (size_t)m0 * K;
    const u16* Bb = Bt + (size_t)n0 * K;
    // staging: LDS pos p (=tid, tid+256) <- row-major chunk c = p ^ ((p>>3)&3)
    const int p0 = tid, p1 = tid + 256;
    const int ch0 = p0 ^ ((p0 >> 3) & 3);
    const int ch1 = p1 ^ ((p1 >> 3) & 3);
    const size_t off0 = (size_t)(ch0 >> 2) * K + (size_t)(ch0 & 3) * 8;
    const size_t off1 = (size_t)(ch1 >> 2) * K + (size_t)(ch1 & 3) * 8;
    u16* As0 = &As[(wid * 64) * 8];
    u16* As1 = &As[(wid * 64 + 256) * 8];
    u16* Bs0 = &Bs[(wid * 64) * 8];
    u16* Bs1 = &Bs[(wid * 64 + 256) * 8];

    for (int k0 = 0; k0 < K; k0 += 32) {
        gload_lds16(Ab + off0 + k0, As0);
        gload_lds16(Ab + off1 + k0, As1);
        gload_lds16(Bb + off0 + k0, Bs0);
        gload_lds16(Bb + off1 + k0, Bs1);
        __syncthreads();
        short8 af[4], bfr[4];
        #pragma unroll
        for (int i = 0; i < 4; i++) {
            int ac = (wr * 64 + i * 16 + (lane & 15)) * 4 + (lane >> 4);
            ac ^= (ac >> 3) & 3;
            af[i] = *(const short8*)&As[ac * 8];
        }
        #pragma unroll
        for (int j = 0; j < 4; j++) {
            int bc = (wc * 64 + j * 16 + (lane & 15)) * 4 + (lane >> 4);
            bc ^= (bc >> 3) & 3;
            bfr[j] = *(const short8*)&Bs[bc * 8];
        }
        #pragma unroll
        for (int i = 0; i < 4; i++) {
            #pragma unroll
            for (int j = 0; j < 4; j++)
                acc[i][j] = __builtin_amdgcn_mfma_f32_16x16x32_bf16(af[i], bfr[j], acc[i][j], 0, 0, 0);
        }
        __syncthreads();
    }

    const int cr = (lane >> 4) * 4, cc = lane & 15;
    #pragma unroll
    for (int i = 0; i < 4; i++) {
        #pragma unroll
        for (int j = 0; j < 4; j++) {
            int row = m0 + wr * 64 + i * 16 + cr;
            int col = n0 + wc * 64 + j * 16 + cc;
            #pragma unroll
            for (int r = 0; r < 4; r++) {
                float v = acc[i][j][r];
                int rr = row + r;
                if (MODE == 0) {
                    ((float*)C)[(size_t)rr * N + col] = v;
                } else if (MODE == 1) {
                    ((u16*)C)[(size_t)rr * N + col] = f2bf(v);
                } else if (MODE == 2) {
                    int h = col >> 6, dd = col & 63;
                    ((u16*)C)[(((size_t)(rr >> 8) * 16 + h) * 256 + (rr & 255)) * 64 + dd] = f2bf(v);
                } else if (MODE == 3) {
                    if (col < 1024) {
                        int h = col >> 6, dd = col & 63;
                        ((u16*)C)[(((size_t)(rr >> 8) * 16 + h) * 256 + (rr & 255)) * 64 + dd] = f2bf(v);
                    } else {
                        int d = col - 1024;
                        int h = d >> 6, dd = d & 63;
                        u16* vt = (u16*)C + (size_t)16384 * 1024;
                        vt[(((size_t)(rr >> 8) * 16 + h) * 64 + dd) * 256 + (rr & 255)] = f2bf(v);
                    }
                } else {  // MODE 4
                    if (col < 1024) {
                        int h = col >> 6, dd = col & 63;
                        ((u16*)C)[(((size_t)(rr >> 8) * 16 + h) * 256 + (rr & 255)) * 64 + dd] = f2bf(v);
                    } else {
                        u16* lat = (u16*)C + (size_t)16384 * 1024;
                        lat[(size_t)rr * 128 + (col - 1024)] = f2bf(v);
                    }
                }
            }
        }
    }
}

// ---------------- causal attention (32x32x16 structure) ----------------
// One block per (b,h), 4 waves. Wave w handles q-blocks {w, 7-w} (balanced: 9 k-tiles).
// Swapped QK^T: s = mfma(K,Q) -> lane owns col q=lane&31, rows k=(r&3)+8(r>>2)+4*hi2.
// P packed to bf16 pairs; permlane32_swap builds the PV A-fragment in-register.
// No max-subtraction (scores bounded); single end-of-row sum reduce.
// LDS = Vt only (33.8 KB).
__global__ __launch_bounds__(256, 3) void attn_kernel(const u16* __restrict__ Qh, const u16* __restrict__ Kh,
                                                      const u16* __restrict__ Vtg, u16* __restrict__ Y) {
    constexpr int T = 256, HD = 1024;
    constexpr int VS = 264;  // Vt row stride (16B-aligned rows)
    __shared__ __align__(16) u16 Vt[64 * VS];

    const int tid = threadIdx.x, lane = tid & 63, wid = tid >> 6;
    const int bh = blockIdx.x;
    const size_t base = (size_t)bh * (T * 64);
    const size_t baseY = (size_t)(bh >> 4) * T * HD + (size_t)(bh & 15) * 64;

    // stage Vt[d][t] from pre-transposed global (coalesced 16B chunks)
    {
        const u16* vsrc = Vtg + base;
        #pragma unroll
        for (int it = 0; it < 8; it++) {
            int idx = tid + it * 256;       // 0..2047
            int d = idx >> 5, t0 = (idx & 31) * 8;
            *(short8*)&Vt[d * VS + t0] = *(const short8*)&vsrc[d * 256 + t0];
        }
    }
    __syncthreads();

    const float c_exp = 0.125f * 1.44269504088896f;  // scale * log2(e)
    const int qcol = lane & 31, hi2 = lane >> 5;
    const u16* kbase = Kh + base;
    const u16* qbase = Qh + base;
    const u16* vrow0 = &Vt[qcol * VS];
    const u16* vrow1 = &Vt[(qcol + 32) * VS];

    #pragma unroll 1
    for (int half = 0; half < 2; half++) {
        const int qb = half ? (7 - wid) : wid;   // wave-uniform q-block 0..7

        short8 qf[4];
        {
            const u16* qp = &qbase[(size_t)(qb * 32 + qcol) * 64 + hi2 * 8];
            #pragma unroll
            for (int i = 0; i < 4; i++) qf[i] = *(const short8*)&qp[i * 16];
        }

        floatx16 y0 = {0}, y1 = {0};
        float lsum = 0.f;

        for (int kt = 0; kt <= qb; kt++) {
            // ---- QK^T (swapped): S[k][q], contraction over d=64 in 4 chunks ----
            const u16* kp = &kbase[(size_t)(kt * 32 + qcol) * 64 + hi2 * 8];
            floatx16 s = {0};
            #pragma unroll
            for (int i = 0; i < 4; i++) {
                short8 kf = *(const short8*)&kp[i * 16];
                s = __builtin_amdgcn_mfma_f32_32x32x16_bf16(kf, qf[i], s, 0, 0, 0);
            }

            // ---- exp (no max-sub), causal mask on diagonal tile, pack bf16 pairs ----
            const bool diag = (kt == qb);
            u32 pk[8];
            #pragma unroll
            for (int r2 = 0; r2 < 8; r2++) {
                const int r0 = 2 * r2;
                const int kr0 = (r0 & 3) + 8 * (r0 >> 2) + 4 * hi2;  // k-row of reg r0
                float p0 = exp2f(s[r0] * c_exp);
                float p1 = exp2f(s[r0 + 1] * c_exp);
                if (diag) {
                    if (kr0 > qcol) p0 = 0.f;
                    if (kr0 + 1 > qcol) p1 = 0.f;
                }
                lsum += p0 + p1;
                pk[r2] = (u32)f2bf(p0) | ((u32)f2bf(p1) << 16);
            }

            // ---- PV: build A-frag via permlane32_swap, 2 k-halves x 2 d-tiles ----
            #pragma unroll
            for (int kh2 = 0; kh2 < 2; kh2++) {
                u32 a0 = pk[kh2 * 4 + 0], a1 = pk[kh2 * 4 + 1];
                u32 b0 = pk[kh2 * 4 + 2], b1 = pk[kh2 * 4 + 3];
                asm volatile("v_permlane32_swap_b32 %0, %1" : "+v"(a0), "+v"(b0));
                asm volatile("v_permlane32_swap_b32 %0, %1" : "+v"(a1), "+v"(b1));
                intx4 w;
                w[0] = (int)a0; w[1] = (int)a1; w[2] = (int)b0; w[3] = (int)b1;
                short8 pa = __builtin_bit_cast(short8, w);
                const int tofs = kt * 32 + kh2 * 16 + hi2 * 8;
                short8 vf0 = *(const short8*)&vrow0[tofs];
                short8 vf1 = *(const short8*)&vrow1[tofs];
                y0 = __builtin_amdgcn_mfma_f32_32x32x16_bf16(pa, vf0, y0, 0, 0, 0);
                y1 = __builtin_amdgcn_mfma_f32_32x32x16_bf16(pa, vf1, y1, 0, 0, 0);
            }
        }

        // ---- row sums (lane q and q+32 hold partials for column q) ----
        lsum += __shfl_xor(lsum, 32);
        const float linv = 1.0f / lsum;

        float sc[16];
        #pragma unroll
        for (int r = 0; r < 16; r++)
            sc[r] = __shfl(linv, (r & 3) + 8 * (r >> 2) + 4 * hi2, 64);

        #pragma unroll
        for (int r = 0; r < 16; r++) {
            const int qloc = (r & 3) + 8 * (r >> 2) + 4 * hi2;
            const size_t rowoff = baseY + (size_t)(qb * 32 + qloc) * HD;
            Y[rowoff + qcol]      = f2bf(y0[r] * sc[r]);
            Y[rowoff + 32 + qcol] = f2bf(y1[r] * sc[r]);
        }
    }
}

extern "C" void kernel_launch(void* const* d_in, const int* in_sizes, int n_in,
                              void* d_out, int out_size, void* d_ws, size_t ws_size,
                              hipStream_t stream) {
    const float* x         = (const float*)d_in[0];
    const float* w_kv_down = (const float*)d_in[1];
    const float* w_kv_up   = (const float*)d_in[2];
    const float* w_q       = (const float*)d_in[3];
    const float* w_out     = (const float*)d_in[4];
    float* out = (float*)d_out;

    constexpr int Bb = 64, Tt = 256, Cc = 1024, HD = 1024, R = 128;
    constexpr int M = Bb * Tt;  // 16384

    char* ws = (char*)d_ws;
    auto alloc = [&](size_t bytes) {
        void* p = (void*)ws;
        ws += (bytes + 255) & ~(size_t)255;
        return p;
    };
    u16* xb      = (u16*)alloc((size_t)M * Cc * 2);
    u16* wql_t   = (u16*)alloc((size_t)(HD + R) * Cc * 2);  // rows 0..1023 = Wq^T, 1024..1151 = Wkv_down^T
    u16* wkvu_t  = (u16*)alloc((size_t)2 * HD * R * 2);
    u16* wo_t    = (u16*)alloc((size_t)Cc * HD * 2);
    u16* qh      = (u16*)alloc((size_t)M * HD * 2);      // per-head packed q  [b][h][t][64]
    u16* latentb = (u16*)alloc((size_t)M * R * 2);       // MUST stay contiguous after qh (MODE 4)
    u16* kvb     = (u16*)alloc((size_t)M * 2 * HD * 2);  // kh [b][h][t][64] then vt [b][h][d][t]
    u16* yb      = (u16*)alloc((size_t)M * HD * 2);

    u16* kh  = kvb;
    u16* vtg = kvb + (size_t)M * HD;

    cvt_x<<<2048, 256, 0, stream>>>(x, xb, M * Cc / 4);
    transpose_cvt<<<dim3(HD / 32, Cc / 32), 256, 0, stream>>>(w_q, wql_t, Cc, HD);
    transpose_cvt<<<dim3(R / 32, Cc / 32), 256, 0, stream>>>(w_kv_down, wql_t + (size_t)HD * Cc, Cc, R);
    transpose_cvt<<<dim3(2 * HD / 32, R / 32), 256, 0, stream>>>(w_kv_up, wkvu_t, R, 2 * HD);
    transpose_cvt<<<dim3(Cc / 32, HD / 32), 256, 0, stream>>>(w_out, wo_t, HD, Cc);

    // q + latent fused: (M x 1152 x 1024); cols 0..1023 -> qh (packed), 1024..1151 -> latentb
    gemm_bt<4><<<dim3(M / 128, (HD + R) / 128), 256, 0, stream>>>(xb, wql_t, qh, M, HD + R, Cc);
    // kv = latent @ Wkv_up    (M x 2048 x 128) -> K per-head packed + V transposed
    gemm_bt<3><<<dim3(M / 128, 2 * HD / 128), 256, 0, stream>>>(latentb, wkvu_t, kvb, M, 2 * HD, R);
    // attention
    attn_kernel<<<Bb * 16, 256, 0, stream>>>(qh, kh, vtg, yb);
    // out = y @ Wout          (M x 1024 x 1024), fp32 [M][1024]
    gemm_bt<0><<<dim3(M / 128, Cc / 128), 256, 0, stream>>>(yb, wo_t, out, M, Cc, HD);
}

// Round 7
// 226.951 us; speedup vs baseline: 1.2860x; 1.0015x over previous
//
#include <hip/hip_runtime.h>
#include <hip/hip_bf16.h>
#include <cstdint>
#include <cstddef>

typedef short short8 __attribute__((ext_vector_type(8)));
typedef float floatx4 __attribute__((ext_vector_type(4)));
typedef float floatx16 __attribute__((ext_vector_type(16)));
typedef int intx4 __attribute__((ext_vector_type(4)));
typedef unsigned short u16;
typedef unsigned int u32;

__device__ __forceinline__ u16 f2bf(float f) {
    __hip_bfloat16 h = __float2bfloat16(f);
    return __builtin_bit_cast(u16, h);
}

__device__ __forceinline__ void gload_lds16(const void* g, void* l) {
    __builtin_amdgcn_global_load_lds(
        (const __attribute__((address_space(1))) void*)g,
        (__attribute__((address_space(3))) void*)l, 16, 0, 0);
}

// ---------------- fp32 -> bf16 elementwise ----------------
__global__ __launch_bounds__(256) void cvt_x(const float* __restrict__ in, u16* __restrict__ out, int n4) {
    int stride = gridDim.x * blockDim.x;
    for (int i = blockIdx.x * blockDim.x + threadIdx.x; i < n4; i += stride) {
        float4 v = ((const float4*)in)[i];
        ushort4 o;
        o.x = f2bf(v.x); o.y = f2bf(v.y); o.z = f2bf(v.z); o.w = f2bf(v.w);
        ((ushort4*)out)[i] = o;
    }
}

// ---------------- W[K][N] f32 -> Wt[N][K] bf16 ----------------
__global__ __launch_bounds__(256) void transpose_cvt(const float* __restrict__ W, u16* __restrict__ Wt,
                                                     int K, int N) {
    __shared__ float tile[32][33];
    int n0 = blockIdx.x * 32, k0 = blockIdx.y * 32;
    int tx = threadIdx.x & 31, ty = threadIdx.x >> 5;  // ty 0..7
    #pragma unroll
    for (int i = 0; i < 32; i += 8)
        tile[ty + i][tx] = W[(size_t)(k0 + ty + i) * N + n0 + tx];
    __syncthreads();
    #pragma unroll
    for (int i = 0; i < 32; i += 8)
        Wt[(size_t)(n0 + ty + i) * K + k0 + tx] = f2bf(tile[tx][ty + i]);
}

// ---------------- deep-pipelined bf16 GEMM: C = A[M][K] * Bt[N][K]^T ----------------
// BM=128, BN=256, BK=64. 512 threads = 8 waves (2 M x 4 N), wave tile 64x64.
// 3 LDS buffers (48KB each = A[128][64] + B[256][64], chunk-XOR swizzled), depth-2
// prefetch with counted vmcnt (12 = 2 tiles x 6 loads in flight across barriers).
// MODE: 0 = f32 [M][N]; 4 = col<1024 -> per-head packed q, 1024<=col<1152 -> latent
//       [M][128] appended after q, col>=1152 -> discard (padding).
template <int MODE>
__global__ __launch_bounds__(512) void gemm8(const u16* __restrict__ A, const u16* __restrict__ Bt,
                                             void* __restrict__ C, int M, int N, int K) {
    constexpr int BUF = 24576;          // u16 elements per buffer (48 KB)
    __shared__ u16 lds[3 * BUF];        // 144 KB
    const int tid = threadIdx.x;
    const int lane = tid & 63, wid = tid >> 6;
    const int wr = wid >> 2, wc = wid & 3;
    const int l15 = lane & 15, hi = lane >> 4;
    const int m0 = blockIdx.x * 128, n0 = blockIdx.y * 256;

    const u16* Ab = A + (size_t)m0 * K;
    const u16* Bb = Bt + (size_t)n0 * K;

    // staging: LDS pos p holds row-major chunk c = p ^ ((p>>3)&7) (involution, stays
    // within its 8-chunk row). Per-wave dest base is uniform; lane lands at +lane*16B.
    size_t asrc[2], bsrc[4];
    #pragma unroll
    for (int l = 0; l < 2; l++) {
        int p = l * 512 + tid, c = p ^ ((p >> 3) & 7);
        asrc[l] = (size_t)(c >> 3) * K + (size_t)(c & 7) * 8;
    }
    #pragma unroll
    for (int l = 0; l < 4; l++) {
        int p = l * 512 + tid, c = p ^ ((p >> 3) & 7);
        bsrc[l] = (size_t)(c >> 3) * K + (size_t)(c & 7) * 8;
    }
    const int wbase = wid * 64;  // wave-uniform lane-0 position within a 512-chunk group

    // fragment read offsets (u16 elements, fixed per buffer)
    int aoff[2][4], boff[2][4];
    #pragma unroll
    for (int ks = 0; ks < 2; ks++) {
        #pragma unroll
        for (int m = 0; m < 4; m++) {
            int row = wr * 64 + m * 16 + l15, ch = ks * 4 + hi;
            int c = row * 8 + ch, p = c ^ (row & 7);
            aoff[ks][m] = p * 8;
        }
        #pragma unroll
        for (int n = 0; n < 4; n++) {
            int row = wc * 64 + n * 16 + l15, ch = ks * 4 + hi;
            int c = row * 8 + ch, p = c ^ (row & 7);
            boff[ks][n] = 8192 + p * 8;
        }
    }

    floatx4 acc[4][4] = {};
    const int NT = K >> 6;  // K multiple of 64, NT >= 3 assumed (K=1024 here)

    auto STAGE = [&](int t, int bufi) {
        u16* buf = &lds[bufi * BUF];
        const size_t k0 = (size_t)t * 64;
        #pragma unroll
        for (int l = 0; l < 2; l++)
            gload_lds16(Ab + asrc[l] + k0, buf + (size_t)(l * 512 + wbase) * 8);
        #pragma unroll
        for (int l = 0; l < 4; l++)
            gload_lds16(Bb + bsrc[l] + k0, buf + 8192 + (size_t)(l * 512 + wbase) * 8);
    };

    STAGE(0, 0);
    STAGE(1, 1);

    int cur = 0;
    for (int t = 0; t < NT; t++) {
        int b2 = cur + 2; if (b2 >= 3) b2 -= 3;
        if (t + 2 < NT) {
            STAGE(t + 2, b2);
            asm volatile("s_waitcnt vmcnt(12)\ns_barrier" ::: "memory");
        } else if (t + 1 < NT) {
            asm volatile("s_waitcnt vmcnt(6)\ns_barrier" ::: "memory");
        } else {
            asm volatile("s_waitcnt vmcnt(0)\ns_barrier" ::: "memory");
        }
        const u16* buf = &lds[cur * BUF];
        #pragma unroll
        for (int ks = 0; ks < 2; ks++) {
            short8 af[4], bfr[4];
            #pragma unroll
            for (int m = 0; m < 4; m++) af[m] = *(const short8*)&buf[aoff[ks][m]];
            #pragma unroll
            for (int n = 0; n < 4; n++) bfr[n] = *(const short8*)&buf[boff[ks][n]];
            __builtin_amdgcn_s_setprio(1);
            #pragma unroll
            for (int m = 0; m < 4; m++) {
                #pragma unroll
                for (int n = 0; n < 4; n++)
                    acc[m][n] = __builtin_amdgcn_mfma_f32_16x16x32_bf16(af[m], bfr[n], acc[m][n], 0, 0, 0);
            }
            __builtin_amdgcn_s_setprio(0);
        }
        asm volatile("s_barrier" ::: "memory");
        cur = (cur == 2) ? 0 : cur + 1;
    }

    const int cr = hi * 4, cc = l15;
    #pragma unroll
    for (int i = 0; i < 4; i++) {
        #pragma unroll
        for (int j = 0; j < 4; j++) {
            int row = m0 + wr * 64 + i * 16 + cr;
            int col = n0 + wc * 64 + j * 16 + cc;
            #pragma unroll
            for (int r = 0; r < 4; r++) {
                float v = acc[i][j][r];
                int rr = row + r;
                if (MODE == 0) {
                    ((float*)C)[(size_t)rr * N + col] = v;
                } else {  // MODE 4
                    if (col < 1024) {
                        int h = col >> 6, dd = col & 63;
                        ((u16*)C)[(((size_t)(rr >> 8) * 16 + h) * 256 + (rr & 255)) * 64 + dd] = f2bf(v);
                    } else if (col < 1152) {
                        u16* lat = (u16*)C + (size_t)16384 * 1024;
                        lat[(size_t)rr * 128 + (col - 1024)] = f2bf(v);
                    }
                }
            }
        }
    }
}

// ---------------- 128x128 single-buffer GEMM (kept for K=128 kv) ----------------
// MODE 3: col<1024 -> K per-head packed; col>=1024 -> V transposed [b][h][d][t]
template <int MODE>
__global__ __launch_bounds__(256) void gemm_bt(const u16* __restrict__ A, const u16* __restrict__ Bt,
                                               void* __restrict__ C, int M, int N, int K) {
    __shared__ u16 As[128 * 32];
    __shared__ u16 Bs[128 * 32];
    const int tid = threadIdx.x;
    const int lane = tid & 63, wid = tid >> 6;
    const int m0 = blockIdx.x * 128, n0 = blockIdx.y * 128;
    const int wr = wid >> 1, wc = wid & 1;

    floatx4 acc[4][4] = {};

    const u16* Ab = A + (size_t)m0 * K;
    const u16* Bb = Bt + (size_t)n0 * K;
    const int p0 = tid, p1 = tid + 256;
    const int ch0 = p0 ^ ((p0 >> 3) & 3);
    const int ch1 = p1 ^ ((p1 >> 3) & 3);
    const size_t off0 = (size_t)(ch0 >> 2) * K + (size_t)(ch0 & 3) * 8;
    const size_t off1 = (size_t)(ch1 >> 2) * K + (size_t)(ch1 & 3) * 8;
    u16* As0 = &As[(wid * 64) * 8];
    u16* As1 = &As[(wid * 64 + 256) * 8];
    u16* Bs0 = &Bs[(wid * 64) * 8];
    u16* Bs1 = &Bs[(wid * 64 + 256) * 8];

    for (int k0 = 0; k0 < K; k0 += 32) {
        gload_lds16(Ab + off0 + k0, As0);
        gload_lds16(Ab + off1 + k0, As1);
        gload_lds16(Bb + off0 + k0, Bs0);
        gload_lds16(Bb + off1 + k0, Bs1);
        __syncthreads();
        short8 af[4], bfr[4];
        #pragma unroll
        for (int i = 0; i < 4; i++) {
            int ac = (wr * 64 + i * 16 + (lane & 15)) * 4 + (lane >> 4);
            ac ^= (ac >> 3) & 3;
            af[i] = *(const short8*)&As[ac * 8];
        }
        #pragma unroll
        for (int j = 0; j < 4; j++) {
            int bc = (wc * 64 + j * 16 + (lane & 15)) * 4 + (lane >> 4);
            bc ^= (bc >> 3) & 3;
            bfr[j] = *(const short8*)&Bs[bc * 8];
        }
        #pragma unroll
        for (int i = 0; i < 4; i++) {
            #pragma unroll
            for (int j = 0; j < 4; j++)
                acc[i][j] = __builtin_amdgcn_mfma_f32_16x16x32_bf16(af[i], bfr[j], acc[i][j], 0, 0, 0);
        }
        __syncthreads();
    }

    const int cr = (lane >> 4) * 4, cc = lane & 15;
    #pragma unroll
    for (int i = 0; i < 4; i++) {
        #pragma unroll
        for (int j = 0; j < 4; j++) {
            int row = m0 + wr * 64 + i * 16 + cr;
            int col = n0 + wc * 64 + j * 16 + cc;
            #pragma unroll
            for (int r = 0; r < 4; r++) {
                float v = acc[i][j][r];
                int rr = row + r;
                if (MODE == 3) {
                    if (col < 1024) {
                        int h = col >> 6, dd = col & 63;
                        ((u16*)C)[(((size_t)(rr >> 8) * 16 + h) * 256 + (rr & 255)) * 64 + dd] = f2bf(v);
                    } else {
                        int d = col - 1024;
                        int h = d >> 6, dd = d & 63;
                        u16* vt = (u16*)C + (size_t)16384 * 1024;
                        vt[(((size_t)(rr >> 8) * 16 + h) * 64 + dd) * 256 + (rr & 255)] = f2bf(v);
                    }
                } else {
                    ((u16*)C)[(size_t)rr * N + col] = f2bf(v);
                }
            }
        }
    }
}

// ---------------- causal attention (32x32x16 structure) ----------------
__global__ __launch_bounds__(256, 3) void attn_kernel(const u16* __restrict__ Qh, const u16* __restrict__ Kh,
                                                      const u16* __restrict__ Vtg, u16* __restrict__ Y) {
    constexpr int T = 256, HD = 1024;
    constexpr int VS = 264;
    __shared__ __align__(16) u16 Vt[64 * VS];

    const int tid = threadIdx.x, lane = tid & 63, wid = tid >> 6;
    const int bh = blockIdx.x;
    const size_t base = (size_t)bh * (T * 64);
    const size_t baseY = (size_t)(bh >> 4) * T * HD + (size_t)(bh & 15) * 64;

    {
        const u16* vsrc = Vtg + base;
        #pragma unroll
        for (int it = 0; it < 8; it++) {
            int idx = tid + it * 256;
            int d = idx >> 5, t0 = (idx & 31) * 8;
            *(short8*)&Vt[d * VS + t0] = *(const short8*)&vsrc[d * 256 + t0];
        }
    }
    __syncthreads();

    const float c_exp = 0.125f * 1.44269504088896f;
    const int qcol = lane & 31, hi2 = lane >> 5;
    const u16* kbase = Kh + base;
    const u16* qbase = Qh + base;
    const u16* vrow0 = &Vt[qcol * VS];
    const u16* vrow1 = &Vt[(qcol + 32) * VS];

    #pragma unroll 1
    for (int half = 0; half < 2; half++) {
        const int qb = half ? (7 - wid) : wid;

        short8 qf[4];
        {
            const u16* qp = &qbase[(size_t)(qb * 32 + qcol) * 64 + hi2 * 8];
            #pragma unroll
            for (int i = 0; i < 4; i++) qf[i] = *(const short8*)&qp[i * 16];
        }

        floatx16 y0 = {0}, y1 = {0};
        float lsum = 0.f;

        for (int kt = 0; kt <= qb; kt++) {
            const u16* kp = &kbase[(size_t)(kt * 32 + qcol) * 64 + hi2 * 8];
            floatx16 s = {0};
            #pragma unroll
            for (int i = 0; i < 4; i++) {
                short8 kf = *(const short8*)&kp[i * 16];
                s = __builtin_amdgcn_mfma_f32_32x32x16_bf16(kf, qf[i], s, 0, 0, 0);
            }

            const bool diag = (kt == qb);
            u32 pk[8];
            #pragma unroll
            for (int r2 = 0; r2 < 8; r2++) {
                const int r0 = 2 * r2;
                const int kr0 = (r0 & 3) + 8 * (r0 >> 2) + 4 * hi2;
                float p0 = exp2f(s[r0] * c_exp);
                float p1 = exp2f(s[r0 + 1] * c_exp);
                if (diag) {
                    if (kr0 > qcol) p0 = 0.f;
                    if (kr0 + 1 > qcol) p1 = 0.f;
                }
                lsum += p0 + p1;
                pk[r2] = (u32)f2bf(p0) | ((u32)f2bf(p1) << 16);
            }

            #pragma unroll
            for (int kh2 = 0; kh2 < 2; kh2++) {
                u32 a0 = pk[kh2 * 4 + 0], a1 = pk[kh2 * 4 + 1];
                u32 b0 = pk[kh2 * 4 + 2], b1 = pk[kh2 * 4 + 3];
                asm volatile("v_permlane32_swap_b32 %0, %1" : "+v"(a0), "+v"(b0));
                asm volatile("v_permlane32_swap_b32 %0, %1" : "+v"(a1), "+v"(b1));
                intx4 w;
                w[0] = (int)a0; w[1] = (int)a1; w[2] = (int)b0; w[3] = (int)b1;
                short8 pa = __builtin_bit_cast(short8, w);
                const int tofs = kt * 32 + kh2 * 16 + hi2 * 8;
                short8 vf0 = *(const short8*)&vrow0[tofs];
                short8 vf1 = *(const short8*)&vrow1[tofs];
                y0 = __builtin_amdgcn_mfma_f32_32x32x16_bf16(pa, vf0, y0, 0, 0, 0);
                y1 = __builtin_amdgcn_mfma_f32_32x32x16_bf16(pa, vf1, y1, 0, 0, 0);
            }
        }

        lsum += __shfl_xor(lsum, 32);
        const float linv = 1.0f / lsum;

        float sc[16];
        #pragma unroll
        for (int r = 0; r < 16; r++)
            sc[r] = __shfl(linv, (r & 3) + 8 * (r >> 2) + 4 * hi2, 64);

        #pragma unroll
        for (int r = 0; r < 16; r++) {
            const int qloc = (r & 3) + 8 * (r >> 2) + 4 * hi2;
            const size_t rowoff = baseY + (size_t)(qb * 32 + qloc) * HD;
            Y[rowoff + qcol]      = f2bf(y0[r] * sc[r]);
            Y[rowoff + 32 + qcol] = f2bf(y1[r] * sc[r]);
        }
    }
}

extern "C" void kernel_launch(void* const* d_in, const int* in_sizes, int n_in,
                              void* d_out, int out_size, void* d_ws, size_t ws_size,
                              hipStream_t stream) {
    const float* x         = (const float*)d_in[0];
    const float* w_kv_down = (const float*)d_in[1];
    const float* w_kv_up   = (const float*)d_in[2];
    const float* w_q       = (const float*)d_in[3];
    const float* w_out     = (const float*)d_in[4];
    float* out = (float*)d_out;

    constexpr int Bb = 64, Tt = 256, Cc = 1024, HD = 1024, R = 128;
    constexpr int M = Bb * Tt;  // 16384

    char* ws = (char*)d_ws;
    auto alloc = [&](size_t bytes) {
        void* p = (void*)ws;
        ws += (bytes + 255) & ~(size_t)255;
        return p;
    };
    u16* xb      = (u16*)alloc((size_t)M * Cc * 2);
    u16* wql_t   = (u16*)alloc((size_t)(HD + 256) * Cc * 2);  // rows 0..1023 Wq^T, 1024..1151 Wkvd^T, rest pad
    u16* wkvu_t  = (u16*)alloc((size_t)2 * HD * R * 2);
    u16* wo_t    = (u16*)alloc((size_t)Cc * HD * 2);
    u16* qh      = (u16*)alloc((size_t)M * HD * 2);      // per-head packed q  [b][h][t][64]
    u16* latentb = (u16*)alloc((size_t)M * R * 2);       // adjacent to qh (MODE 4 epilogue)
    u16* kvb     = (u16*)alloc((size_t)M * 2 * HD * 2);  // kh [b][h][t][64] then vt [b][h][d][t]
    u16* yb      = (u16*)alloc((size_t)M * HD * 2);

    u16* kh  = kvb;
    u16* vtg = kvb + (size_t)M * HD;

    cvt_x<<<2048, 256, 0, stream>>>(x, xb, M * Cc / 4);
    transpose_cvt<<<dim3(HD / 32, Cc / 32), 256, 0, stream>>>(w_q, wql_t, Cc, HD);
    transpose_cvt<<<dim3(R / 32, Cc / 32), 256, 0, stream>>>(w_kv_down, wql_t + (size_t)HD * Cc, Cc, R);
    transpose_cvt<<<dim3(2 * HD / 32, R / 32), 256, 0, stream>>>(w_kv_up, wkvu_t, R, 2 * HD);
    transpose_cvt<<<dim3(Cc / 32, HD / 32), 256, 0, stream>>>(w_out, wo_t, HD, Cc);

    // q + latent fused (padded to N=1280): cols 0..1023 -> qh, 1024..1151 -> latentb, rest discarded
    gemm8<4><<<dim3(M / 128, 5), 512, 0, stream>>>(xb, wql_t, qh, M, 1280, Cc);
    // kv = latent @ Wkv_up (M x 2048 x 128) -> K per-head packed + V transposed
    gemm_bt<3><<<dim3(M / 128, 2 * HD / 128), 256, 0, stream>>>(latentb, wkvu_t, kvb, M, 2 * HD, R);
    // attention
    attn_kernel<<<Bb * 16, 256, 0, stream>>>(qh, kh, vtg, yb);
    // out = y @ Wout (M x 1024 x 1024), fp32
    gemm8<0><<<dim3(M / 128, 4), 512, 0, stream>>>(yb, wo_t, out, M, Cc, HD);
}

// Round 8
// 223.103 us; speedup vs baseline: 1.3082x; 1.0172x over previous
//
#include <hip/hip_runtime.h>
#include <hip/hip_bf16.h>
#include <cstdint>
#include <cstddef>

typedef short short8 __attribute__((ext_vector_type(8)));
typedef float floatx4 __attribute__((ext_vector_type(4)));
typedef float floatx16 __attribute__((ext_vector_type(16)));
typedef int intx4 __attribute__((ext_vector_type(4)));
typedef unsigned short u16;
typedef unsigned int u32;

__device__ __forceinline__ u16 f2bf(float f) {
    __hip_bfloat16 h = __float2bfloat16(f);
    return __builtin_bit_cast(u16, h);
}

__device__ __forceinline__ void gload_lds16(const void* g, void* l) {
    __builtin_amdgcn_global_load_lds(
        (const __attribute__((address_space(1))) void*)g,
        (__attribute__((address_space(3))) void*)l, 16, 0, 0);
}

// ---------------- fp32 -> bf16 elementwise ----------------
__global__ __launch_bounds__(256) void cvt_x(const float* __restrict__ in, u16* __restrict__ out, int n4) {
    int stride = gridDim.x * blockDim.x;
    for (int i = blockIdx.x * blockDim.x + threadIdx.x; i < n4; i += stride) {
        float4 v = ((const float4*)in)[i];
        ushort4 o;
        o.x = f2bf(v.x); o.y = f2bf(v.y); o.z = f2bf(v.z); o.w = f2bf(v.w);
        ((ushort4*)out)[i] = o;
    }
}

// ---------------- W[K][N] f32 -> Wt[N][K] bf16 ----------------
__global__ __launch_bounds__(256) void transpose_cvt(const float* __restrict__ W, u16* __restrict__ Wt,
                                                     int K, int N) {
    __shared__ float tile[32][33];
    int n0 = blockIdx.x * 32, k0 = blockIdx.y * 32;
    int tx = threadIdx.x & 31, ty = threadIdx.x >> 5;  // ty 0..7
    #pragma unroll
    for (int i = 0; i < 32; i += 8)
        tile[ty + i][tx] = W[(size_t)(k0 + ty + i) * N + n0 + tx];
    __syncthreads();
    #pragma unroll
    for (int i = 0; i < 32; i += 8)
        Wt[(size_t)(n0 + ty + i) * K + k0 + tx] = f2bf(tile[tx][ty + i]);
}

// ---------------- 256x256 deep-pipelined bf16 GEMM: C = A[M][K] * Bt[N][K]^T --------
// BK=64, 512 threads = 8 waves (2M x 4N), wave tile 128x64, acc 8x4 floatx4.
// LDS: 2 dbufs x (A 256x64 + B 256x64) x 2B = 128 KB, chunk-XOR involution swizzle
// (0-conflict measured r6/r7). Staging runs 2 K-tiles ahead into the dbuf the body
// just consumed; per-body: vmcnt(8)+barrier / reads ks0 / MFMA ks0 (overlaps ks1
// reads) / reads ks1 / lgkmcnt(0)+barrier / STAGE(kt+2) / MFMA ks1. vmcnt never
// drains mid-loop. Grid is 1-D with bijective XCD swizzle (nwg % 8 == 0).
// MODE: 0 = f32 [M][N]; 4 = col<1024 -> per-head packed q [b][h][t][64],
//       1024<=col<1152 -> latent [M][128] appended after q; col>=1152 discarded.
template <int MODE>
__global__ __launch_bounds__(512, 2) void gemm256(const u16* __restrict__ A, const u16* __restrict__ Bt,
                                                  void* __restrict__ C, int M, int N, int K, int nwgx) {
    __shared__ __align__(16) u16 lds[65536];  // 128 KB
    const int tid = threadIdx.x;
    const int lane = tid & 63, wid = tid >> 6;
    const int wr = wid >> 2, wc = wid & 3;
    const int l15 = lane & 15, hi = lane >> 4;

    // bijective XCD swizzle (nwg multiple of 8)
    const int nwg = gridDim.x;
    const int qch = nwg >> 3;
    const int wg = (blockIdx.x & 7) * qch + (blockIdx.x >> 3);
    const int mx = wg % nwgx, nx = wg / nwgx;
    const int m0 = mx * 256, n0 = nx * 256;

    const u16* Ab = A + (size_t)m0 * K;
    const u16* Bb = Bt + (size_t)n0 * K;

    // staging source offsets: LDS position p holds row-major chunk c = p ^ ((p>>3)&7)
    u32 asrc[4];
    #pragma unroll
    for (int l = 0; l < 4; l++) {
        int p = l * 512 + tid, c = p ^ ((p >> 3) & 7);
        asrc[l] = (u32)((c >> 3) * K + (c & 7) * 8);
    }
    const int wbase = wid * 64;

    // fragment read offsets for ks=0 (ks=1 = ^32 in element units)
    int aoff0[8], boff0[4];
    #pragma unroll
    for (int i = 0; i < 8; i++) {
        int row = wr * 128 + i * 16 + l15;
        int c = row * 8 + hi, p = c ^ (row & 7);
        aoff0[i] = p * 8;
    }
    #pragma unroll
    for (int n = 0; n < 4; n++) {
        int row = wc * 64 + n * 16 + l15;
        int c = row * 8 + hi, p = c ^ (row & 7);
        boff0[n] = 16384 + p * 8;
    }

    floatx4 acc[8][4] = {};
    const int NT = K >> 6;

    auto STAGE = [&](int t) {
        u16* buf = &lds[(t & 1) * 32768];
        const size_t k0 = (size_t)t * 64;
        #pragma unroll
        for (int l = 0; l < 4; l++)
            gload_lds16(Ab + asrc[l] + k0, buf + (size_t)(l * 512 + wbase) * 8);
        #pragma unroll
        for (int l = 0; l < 4; l++)
            gload_lds16(Bb + asrc[l] + k0, buf + 16384 + (size_t)(l * 512 + wbase) * 8);
    };

    STAGE(0);
    STAGE(1);

    for (int kt = 0; kt < NT; kt++) {
        if (kt + 1 < NT) {
            asm volatile("s_waitcnt vmcnt(8)\ns_barrier" ::: "memory");
        } else {
            asm volatile("s_waitcnt vmcnt(0)\ns_barrier" ::: "memory");
        }
        const u16* buf = &lds[(kt & 1) * 32768];

        // ---- ks = 0 fragments ----
        short8 af0[8], bf0[4];
        #pragma unroll
        for (int i = 0; i < 8; i++) af0[i] = *(const short8*)&buf[aoff0[i]];
        #pragma unroll
        for (int n = 0; n < 4; n++) bf0[n] = *(const short8*)&buf[boff0[n]];
        __builtin_amdgcn_s_setprio(1);
        #pragma unroll
        for (int i = 0; i < 8; i++) {
            #pragma unroll
            for (int n = 0; n < 4; n++)
                acc[i][n] = __builtin_amdgcn_mfma_f32_16x16x32_bf16(af0[i], bf0[n], acc[i][n], 0, 0, 0);
        }
        __builtin_amdgcn_s_setprio(0);

        // ---- ks = 1 fragments (overlap with ks0 MFMA via compiler scheduling) ----
        short8 af1[8], bf1[4];
        #pragma unroll
        for (int i = 0; i < 8; i++) af1[i] = *(const short8*)&buf[aoff0[i] ^ 32];
        #pragma unroll
        for (int n = 0; n < 4; n++) bf1[n] = *(const short8*)&buf[boff0[n] ^ 32];

        // all reads of this dbuf retired block-wide -> safe to overwrite
        asm volatile("s_waitcnt lgkmcnt(0)\ns_barrier" ::: "memory");
        if (kt + 2 < NT) STAGE(kt + 2);

        __builtin_amdgcn_s_setprio(1);
        #pragma unroll
        for (int i = 0; i < 8; i++) {
            #pragma unroll
            for (int n = 0; n < 4; n++)
                acc[i][n] = __builtin_amdgcn_mfma_f32_16x16x32_bf16(af1[i], bf1[n], acc[i][n], 0, 0, 0);
        }
        __builtin_amdgcn_s_setprio(0);
    }

    // ---- epilogue ----
    #pragma unroll
    for (int i = 0; i < 8; i++) {
        #pragma unroll
        for (int n = 0; n < 4; n++) {
            int row = m0 + wr * 128 + i * 16 + hi * 4;
            int col = n0 + wc * 64 + n * 16 + l15;
            #pragma unroll
            for (int r = 0; r < 4; r++) {
                float v = acc[i][n][r];
                int rr = row + r;
                if (MODE == 0) {
                    ((float*)C)[(size_t)rr * N + col] = v;
                } else {  // MODE 4
                    if (col < 1024) {
                        int h = col >> 6, dd = col & 63;
                        ((u16*)C)[(((size_t)(rr >> 8) * 16 + h) * 256 + (rr & 255)) * 64 + dd] = f2bf(v);
                    } else if (col < 1152) {
                        u16* lat = (u16*)C + (size_t)16384 * 1024;
                        lat[(size_t)rr * 128 + (col - 1024)] = f2bf(v);
                    }
                }
            }
        }
    }
}

// ---------------- 128x128 single-buffer GEMM (kept for K=128 kv) ----------------
// MODE 3: col<1024 -> K per-head packed; col>=1024 -> V transposed [b][h][d][t]
template <int MODE>
__global__ __launch_bounds__(256) void gemm_bt(const u16* __restrict__ A, const u16* __restrict__ Bt,
                                               void* __restrict__ C, int M, int N, int K) {
    __shared__ u16 As[128 * 32];
    __shared__ u16 Bs[128 * 32];
    const int tid = threadIdx.x;
    const int lane = tid & 63, wid = tid >> 6;
    const int m0 = blockIdx.x * 128, n0 = blockIdx.y * 128;
    const int wr = wid >> 1, wc = wid & 1;

    floatx4 acc[4][4] = {};

    const u16* Ab = A + (size_t)m0 * K;
    const u16* Bb = Bt + (size_t)n0 * K;
    const int p0 = tid, p1 = tid + 256;
    const int ch0 = p0 ^ ((p0 >> 3) & 3);
    const int ch1 = p1 ^ ((p1 >> 3) & 3);
    const size_t off0 = (size_t)(ch0 >> 2) * K + (size_t)(ch0 & 3) * 8;
    const size_t off1 = (size_t)(ch1 >> 2) * K + (size_t)(ch1 & 3) * 8;
    u16* As0 = &As[(wid * 64) * 8];
    u16* As1 = &As[(wid * 64 + 256) * 8];
    u16* Bs0 = &Bs[(wid * 64) * 8];
    u16* Bs1 = &Bs[(wid * 64 + 256) * 8];

    for (int k0 = 0; k0 < K; k0 += 32) {
        gload_lds16(Ab + off0 + k0, As0);
        gload_lds16(Ab + off1 + k0, As1);
        gload_lds16(Bb + off0 + k0, Bs0);
        gload_lds16(Bb + off1 + k0, Bs1);
        __syncthreads();
        short8 af[4], bfr[4];
        #pragma unroll
        for (int i = 0; i < 4; i++) {
            int ac = (wr * 64 + i * 16 + (lane & 15)) * 4 + (lane >> 4);
            ac ^= (ac >> 3) & 3;
            af[i] = *(const short8*)&As[ac * 8];
        }
        #pragma unroll
        for (int j = 0; j < 4; j++) {
            int bc = (wc * 64 + j * 16 + (lane & 15)) * 4 + (lane >> 4);
            bc ^= (bc >> 3) & 3;
            bfr[j] = *(const short8*)&Bs[bc * 8];
        }
        #pragma unroll
        for (int i = 0; i < 4; i++) {
            #pragma unroll
            for (int j = 0; j < 4; j++)
                acc[i][j] = __builtin_amdgcn_mfma_f32_16x16x32_bf16(af[i], bfr[j], acc[i][j], 0, 0, 0);
        }
        __syncthreads();
    }

    const int cr = (lane >> 4) * 4, cc = lane & 15;
    #pragma unroll
    for (int i = 0; i < 4; i++) {
        #pragma unroll
        for (int j = 0; j < 4; j++) {
            int row = m0 + wr * 64 + i * 16 + cr;
            int col = n0 + wc * 64 + j * 16 + cc;
            #pragma unroll
            for (int r = 0; r < 4; r++) {
                float v = acc[i][j][r];
                int rr = row + r;
                if (MODE == 3) {
                    if (col < 1024) {
                        int h = col >> 6, dd = col & 63;
                        ((u16*)C)[(((size_t)(rr >> 8) * 16 + h) * 256 + (rr & 255)) * 64 + dd] = f2bf(v);
                    } else {
                        int d = col - 1024;
                        int h = d >> 6, dd = d & 63;
                        u16* vt = (u16*)C + (size_t)16384 * 1024;
                        vt[(((size_t)(rr >> 8) * 16 + h) * 64 + dd) * 256 + (rr & 255)] = f2bf(v);
                    }
                } else {
                    ((u16*)C)[(size_t)rr * N + col] = f2bf(v);
                }
            }
        }
    }
}

// ---------------- causal attention (32x32x16 structure) ----------------
__global__ __launch_bounds__(256, 3) void attn_kernel(const u16* __restrict__ Qh, const u16* __restrict__ Kh,
                                                      const u16* __restrict__ Vtg, u16* __restrict__ Y) {
    constexpr int T = 256, HD = 1024;
    constexpr int VS = 264;
    __shared__ __align__(16) u16 Vt[64 * VS];

    const int tid = threadIdx.x, lane = tid & 63, wid = tid >> 6;
    const int bh = blockIdx.x;
    const size_t base = (size_t)bh * (T * 64);
    const size_t baseY = (size_t)(bh >> 4) * T * HD + (size_t)(bh & 15) * 64;

    {
        const u16* vsrc = Vtg + base;
        #pragma unroll
        for (int it = 0; it < 8; it++) {
            int idx = tid + it * 256;
            int d = idx >> 5, t0 = (idx & 31) * 8;
            *(short8*)&Vt[d * VS + t0] = *(const short8*)&vsrc[d * 256 + t0];
        }
    }
    __syncthreads();

    const float c_exp = 0.125f * 1.44269504088896f;
    const int qcol = lane & 31, hi2 = lane >> 5;
    const u16* kbase = Kh + base;
    const u16* qbase = Qh + base;
    const u16* vrow0 = &Vt[qcol * VS];
    const u16* vrow1 = &Vt[(qcol + 32) * VS];

    #pragma unroll 1
    for (int half = 0; half < 2; half++) {
        const int qb = half ? (7 - wid) : wid;

        short8 qf[4];
        {
            const u16* qp = &qbase[(size_t)(qb * 32 + qcol) * 64 + hi2 * 8];
            #pragma unroll
            for (int i = 0; i < 4; i++) qf[i] = *(const short8*)&qp[i * 16];
        }

        floatx16 y0 = {0}, y1 = {0};
        float lsum = 0.f;

        for (int kt = 0; kt <= qb; kt++) {
            const u16* kp = &kbase[(size_t)(kt * 32 + qcol) * 64 + hi2 * 8];
            floatx16 s = {0};
            #pragma unroll
            for (int i = 0; i < 4; i++) {
                short8 kf = *(const short8*)&kp[i * 16];
                s = __builtin_amdgcn_mfma_f32_32x32x16_bf16(kf, qf[i], s, 0, 0, 0);
            }

            const bool diag = (kt == qb);
            u32 pk[8];
            #pragma unroll
            for (int r2 = 0; r2 < 8; r2++) {
                const int r0 = 2 * r2;
                const int kr0 = (r0 & 3) + 8 * (r0 >> 2) + 4 * hi2;
                float p0 = exp2f(s[r0] * c_exp);
                float p1 = exp2f(s[r0 + 1] * c_exp);
                if (diag) {
                    if (kr0 > qcol) p0 = 0.f;
                    if (kr0 + 1 > qcol) p1 = 0.f;
                }
                lsum += p0 + p1;
                pk[r2] = (u32)f2bf(p0) | ((u32)f2bf(p1) << 16);
            }

            #pragma unroll
            for (int kh2 = 0; kh2 < 2; kh2++) {
                u32 a0 = pk[kh2 * 4 + 0], a1 = pk[kh2 * 4 + 1];
                u32 b0 = pk[kh2 * 4 + 2], b1 = pk[kh2 * 4 + 3];
                asm volatile("v_permlane32_swap_b32 %0, %1" : "+v"(a0), "+v"(b0));
                asm volatile("v_permlane32_swap_b32 %0, %1" : "+v"(a1), "+v"(b1));
                intx4 w;
                w[0] = (int)a0; w[1] = (int)a1; w[2] = (int)b0; w[3] = (int)b1;
                short8 pa = __builtin_bit_cast(short8, w);
                const int tofs = kt * 32 + kh2 * 16 + hi2 * 8;
                short8 vf0 = *(const short8*)&vrow0[tofs];
                short8 vf1 = *(const short8*)&vrow1[tofs];
                y0 = __builtin_amdgcn_mfma_f32_32x32x16_bf16(pa, vf0, y0, 0, 0, 0);
                y1 = __builtin_amdgcn_mfma_f32_32x32x16_bf16(pa, vf1, y1, 0, 0, 0);
            }
        }

        lsum += __shfl_xor(lsum, 32);
        const float linv = 1.0f / lsum;

        float sc[16];
        #pragma unroll
        for (int r = 0; r < 16; r++)
            sc[r] = __shfl(linv, (r & 3) + 8 * (r >> 2) + 4 * hi2, 64);

        #pragma unroll
        for (int r = 0; r < 16; r++) {
            const int qloc = (r & 3) + 8 * (r >> 2) + 4 * hi2;
            const size_t rowoff = baseY + (size_t)(qb * 32 + qloc) * HD;
            Y[rowoff + qcol]      = f2bf(y0[r] * sc[r]);
            Y[rowoff + 32 + qcol] = f2bf(y1[r] * sc[r]);
        }
    }
}

extern "C" void kernel_launch(void* const* d_in, const int* in_sizes, int n_in,
                              void* d_out, int out_size, void* d_ws, size_t ws_size,
                              hipStream_t stream) {
    const float* x         = (const float*)d_in[0];
    const float* w_kv_down = (const float*)d_in[1];
    const float* w_kv_up   = (const float*)d_in[2];
    const float* w_q       = (const float*)d_in[3];
    const float* w_out     = (const float*)d_in[4];
    float* out = (float*)d_out;

    constexpr int Bb = 64, Tt = 256, Cc = 1024, HD = 1024, R = 128;
    constexpr int M = Bb * Tt;  // 16384

    char* ws = (char*)d_ws;
    auto alloc = [&](size_t bytes) {
        void* p = (void*)ws;
        ws += (bytes + 255) & ~(size_t)255;
        return p;
    };
    u16* xb      = (u16*)alloc((size_t)M * Cc * 2);
    u16* wql_t   = (u16*)alloc((size_t)(HD + 256) * Cc * 2);  // rows 0..1023 Wq^T, 1024..1151 Wkvd^T, rest pad
    u16* wkvu_t  = (u16*)alloc((size_t)2 * HD * R * 2);
    u16* wo_t    = (u16*)alloc((size_t)Cc * HD * 2);
    u16* qh      = (u16*)alloc((size_t)M * HD * 2);      // per-head packed q  [b][h][t][64]
    u16* latentb = (u16*)alloc((size_t)M * R * 2);       // adjacent to qh (MODE 4 epilogue)
    u16* kvb     = (u16*)alloc((size_t)M * 2 * HD * 2);  // kh [b][h][t][64] then vt [b][h][d][t]
    u16* yb      = (u16*)alloc((size_t)M * HD * 2);

    u16* kh  = kvb;
    u16* vtg = kvb + (size_t)M * HD;

    cvt_x<<<2048, 256, 0, stream>>>(x, xb, M * Cc / 4);
    transpose_cvt<<<dim3(HD / 32, Cc / 32), 256, 0, stream>>>(w_q, wql_t, Cc, HD);
    transpose_cvt<<<dim3(R / 32, Cc / 32), 256, 0, stream>>>(w_kv_down, wql_t + (size_t)HD * Cc, Cc, R);
    transpose_cvt<<<dim3(2 * HD / 32, R / 32), 256, 0, stream>>>(w_kv_up, wkvu_t, R, 2 * HD);
    transpose_cvt<<<dim3(Cc / 32, HD / 32), 256, 0, stream>>>(w_out, wo_t, HD, Cc);

    // q + latent fused (N padded to 1280): cols 0..1023 -> qh, 1024..1151 -> latentb
    gemm256<4><<<dim3((M / 256) * 5), 512, 0, stream>>>(xb, wql_t, qh, M, 1280, Cc, M / 256);
    // kv = latent @ Wkv_up (M x 2048 x 128) -> K per-head packed + V transposed
    gemm_bt<3><<<dim3(M / 128, 2 * HD / 128), 256, 0, stream>>>(latentb, wkvu_t, kvb, M, 2 * HD, R);
    // attention
    attn_kernel<<<Bb * 16, 256, 0, stream>>>(qh, kh, vtg, yb);
    // out = y @ Wout (M x 1024 x 1024), fp32
    gemm256<0><<<dim3((M / 256) * 4), 512, 0, stream>>>(yb, wo_t, out, M, Cc, HD, M / 256);
}